// Round 2
// baseline (89.195 us; speedup 1.0000x reference)
//
#include <hip/hip_runtime.h>

#define NSHAPES 32
#define BLOCK 256
#define PPT 4   // points per thread (2 packed point-pairs)

// Rotated-rect SDF, min over 32 shapes, per query point.
//
// Round-2: issue-slot reduction 13 -> 9 per shape-point.
//  - v_pk_fma_f32 / v_pk_mul_f32: rotation + square packed across point PAIRS
//    (two points share all shape constants). <2 x float> fma selects packed
//    FP32 on gfx90a+/gfx950.
//  - shapes processed in pairs so accumulator updates fuse to v_min3_f32:
//    acc = min(min(sqA, sqB), acc) -> 1 instr per point per 2 shapes.
//  - epilogue sqrt via raw v_sqrt_f32 (tolerance 7.8e-3 >> 1 ulp), avoids
//    libm IEEE expansion.
//  - minIn initialized to 0 so the inside-clamp min(m,0) is folded into the
//    running min (unchanged from baseline).
// Per shape-point slots: rot 2 (pk) + dx,dy 2 (sub w/ |.| mod) + m 1 +
//   mx,my 2 + sq 1 (pk) + accum 1 (min3) = 9.

typedef float v2f __attribute__((ext_vector_type(2)));

static __device__ __forceinline__ v2f splat(float x) { return (v2f){x, x}; }

template<bool GUARD>
__global__ __launch_bounds__(BLOCK, 8) void multi_rect_sdf_kernel(
    const float4* __restrict__ query4,   // n_f4 float4s = 2 points each
    const float*  __restrict__ trans,    // (32,2)
    const float*  __restrict__ rads,     // (32,2)
    const float*  __restrict__ angles,   // (32,)
    float2*       __restrict__ out2,     // n_f4 float2s
    int n_f4)
{
    __shared__ float4 A[NSHAPES];  // {c, s, tx, ty}
    __shared__ float2 B[NSHAPES];  // {radx, rady}

    const int t = threadIdx.x;
    if (t < NSHAPES) {
        float a = angles[t];
        // |a| < 0.1: HW v_cos/v_sin exact to ~1e-7 here, no libm slow path.
        A[t] = make_float4(__cosf(a), __sinf(a), trans[2 * t], trans[2 * t + 1]);
        B[t] = make_float2(rads[2 * t], rads[2 * t + 1]);
    }
    __syncthreads();

    const int f4_per_block = BLOCK * PPT / 2;  // 512
    const int base = blockIdx.x * f4_per_block + t;

    // Coalesced float4 loads; each is one packed point-pair.
    v2f qxv[PPT / 2], qyv[PPT / 2];
    #pragma unroll
    for (int j = 0; j < PPT / 2; ++j) {
        int idx = base + j * BLOCK;
        float4 q;
        if (!GUARD || idx < n_f4) q = query4[idx];
        else                      q = make_float4(0.f, 0.f, 0.f, 0.f);
        qxv[j] = (v2f){q.x, q.z};
        qyv[j] = (v2f){q.y, q.w};
    }

    v2f minSq[PPT / 2], minIn[PPT / 2];
    #pragma unroll
    for (int j = 0; j < PPT / 2; ++j) {
        minSq[j] = splat(3.0e38f);
        minIn[j] = splat(0.0f);
    }

    #pragma unroll 2
    for (int k = 0; k < NSHAPES; k += 2) {
        float4 a0 = A[k], a1 = A[k + 1];     // broadcast ds_read_b128
        float2 b0 = B[k], b1 = B[k + 1];     // broadcast ds_read_b64
        #pragma unroll
        for (int j = 0; j < PPT / 2; ++j) {
            v2f X = qxv[j], Y = qyv[j];

            // Rotation+translate, packed across the point pair: 4 pk_fma/shape-pair... 2 per shape.
            v2f rx0 = __builtin_elementwise_fma(splat(a0.x), X,
                      __builtin_elementwise_fma(splat(-a0.y), Y, splat(-a0.z)));
            v2f ry0 = __builtin_elementwise_fma(splat(a0.y), X,
                      __builtin_elementwise_fma(splat(a0.x), Y, splat(-a0.w)));
            v2f rx1 = __builtin_elementwise_fma(splat(a1.x), X,
                      __builtin_elementwise_fma(splat(-a1.y), Y, splat(-a1.z)));
            v2f ry1 = __builtin_elementwise_fma(splat(a1.y), X,
                      __builtin_elementwise_fma(splat(a1.x), Y, splat(-a1.w)));

            // dx/dy: v_sub_f32 with |src| modifier (scalar; VOP3P has no abs).
            float dx00 = fabsf(rx0[0]) - b0.x, dy00 = fabsf(ry0[0]) - b0.y;
            float dx01 = fabsf(rx0[1]) - b0.x, dy01 = fabsf(ry0[1]) - b0.y;
            float dx10 = fabsf(rx1[0]) - b1.x, dy10 = fabsf(ry1[0]) - b1.y;
            float dx11 = fabsf(rx1[1]) - b1.x, dy11 = fabsf(ry1[1]) - b1.y;

            float m00 = fmaxf(dx00, dy00), m01 = fmaxf(dx01, dy01);
            float m10 = fmaxf(dx10, dy10), m11 = fmaxf(dx11, dy11);

            v2f mx0 = {fmaxf(dx00, 0.f), fmaxf(dx01, 0.f)};
            v2f my0 = {fmaxf(dy00, 0.f), fmaxf(dy01, 0.f)};
            v2f mx1 = {fmaxf(dx10, 0.f), fmaxf(dx11, 0.f)};
            v2f my1 = {fmaxf(dy10, 0.f), fmaxf(dy11, 0.f)};

            // Squared outside distance, packed: pk_mul + pk_fma per shape.
            v2f sq0 = __builtin_elementwise_fma(mx0, mx0, my0 * my0);
            v2f sq1 = __builtin_elementwise_fma(mx1, mx1, my1 * my1);

            // Accumulate both shapes at once -> v_min3_f32 per point.
            minSq[j][0] = fminf(fminf(sq0[0], sq1[0]), minSq[j][0]);
            minSq[j][1] = fminf(fminf(sq0[1], sq1[1]), minSq[j][1]);
            minIn[j][0] = fminf(fminf(m00, m10), minIn[j][0]);
            minIn[j][1] = fminf(fminf(m01, m11), minIn[j][1]);
        }
    }

    #pragma unroll
    for (int j = 0; j < PPT / 2; ++j) {
        int idx = base + j * BLOCK;
        if (!GUARD || idx < n_f4) {
            float r0 = (minIn[j][0] < 0.0f) ? minIn[j][0]
                                            : __builtin_amdgcn_sqrtf(minSq[j][0]);
            float r1 = (minIn[j][1] < 0.0f) ? minIn[j][1]
                                            : __builtin_amdgcn_sqrtf(minSq[j][1]);
            out2[idx] = make_float2(r0, r1);
        }
    }
}

extern "C" void kernel_launch(void* const* d_in, const int* in_sizes, int n_in,
                              void* d_out, int out_size, void* d_ws, size_t ws_size,
                              hipStream_t stream) {
    const float* query  = (const float*)d_in[0];
    const float* trans  = (const float*)d_in[1];
    const float* rads   = (const float*)d_in[2];
    const float* angles = (const float*)d_in[3];
    float* out = (float*)d_out;

    const int n_points = in_sizes[0] / 2;   // (N,2) -> N
    const int n_f4 = n_points / 2;          // 2 points per float4
    const int f4_per_block = BLOCK * PPT / 2;
    const int grid = (n_f4 + f4_per_block - 1) / f4_per_block;

    if (n_f4 % f4_per_block == 0) {
        multi_rect_sdf_kernel<false><<<grid, BLOCK, 0, stream>>>(
            (const float4*)query, trans, rads, angles, (float2*)out, n_f4);
    } else {
        multi_rect_sdf_kernel<true><<<grid, BLOCK, 0, stream>>>(
            (const float4*)query, trans, rads, angles, (float2*)out, n_f4);
    }
}

// Round 3
// 86.596 us; speedup vs baseline: 1.0300x; 1.0300x over previous
//
#include <hip/hip_runtime.h>

#define NSHAPES 32
#define BLOCK 256
#define PPT 4   // points per thread = 2 packed point-pairs

// Rotated-rect SDF, min over 32 shapes, per query point.
//
// Round-3: clean packed-FP32 codegen (round 2 drowned v_pk ops in scalar
// element extracts; this version keeps v2f end-to-end, no round-trips).
// Per shape per point, issue slots:
//   rot:  2x pk_fma chains -> 4 pk ops / 2 points            = 2
//   dx,dy: scalar v_sub_f32 with |src| modifier, 4 / 2 pts   = 2
//   m = max(dx,dy): scalar, 2 / 2 pts                        = 1
//   mx,my = max(d,0): scalar, 4 / 2 pts                      = 2
//   sq: pk_mul + pk_fma / 2 pts                              = 1
//   accum over shape PAIR: v_min3_f32 x2 per pt-pair / 2 sh  = 1
//   total                                                    = 9  (was 13)
// VALU-issue floor: 2M pts * 32 sh * 9 slots * 2cyc / 1024 SIMDs / 2.4GHz
//   ~= 7.7 us.
// Epilogue: minIn<0 ? minIn : v_sqrt_f32(minSq)  (tolerance 7.8e-3 >> 1 ulp).

typedef float v2f __attribute__((ext_vector_type(2)));

static __device__ __forceinline__ v2f splat(float x) { return (v2f){x, x}; }

// One shape applied to one packed point-pair -> m (inside metric), sq (outside^2)
static __device__ __forceinline__ void shape_pp(
    float c, float s, float tx, float ty, float rdx, float rdy,
    v2f X, v2f Y, v2f& m, v2f& sq)
{
    // rx = c*X - s*Y - tx ; ry = s*X + c*Y - ty   (v_pk_fma_f32 x4)
    v2f rx = __builtin_elementwise_fma(splat(c), X,
             __builtin_elementwise_fma(splat(-s), Y, splat(-tx)));
    v2f ry = __builtin_elementwise_fma(splat(s), X,
             __builtin_elementwise_fma(splat(c), Y, splat(-ty)));
    // dx = |rx| - rdx  (scalar v_sub with abs modifier; no packed f32 sub/abs)
    v2f dx = {fabsf(rx[0]) - rdx, fabsf(rx[1]) - rdx};
    v2f dy = {fabsf(ry[0]) - rdy, fabsf(ry[1]) - rdy};
    m  = (v2f){fmaxf(dx[0], dy[0]), fmaxf(dx[1], dy[1])};
    v2f mx = {fmaxf(dx[0], 0.f), fmaxf(dx[1], 0.f)};
    v2f my = {fmaxf(dy[0], 0.f), fmaxf(dy[1], 0.f)};
    // sq = mx*mx + my*my  (v_pk_mul_f32 + v_pk_fma_f32)
    sq = __builtin_elementwise_fma(mx, mx, my * my);
}

template<bool GUARD>
__global__ __launch_bounds__(BLOCK, 8) void multi_rect_sdf_kernel(
    const float4* __restrict__ query4,   // n_f4 float4s = 2 points each
    const float*  __restrict__ trans,    // (32,2)
    const float*  __restrict__ rads,     // (32,2)
    const float*  __restrict__ angles,   // (32,)
    float2*       __restrict__ out2,     // n_f4 float2s
    int n_f4)
{
    __shared__ float4 A[NSHAPES];  // {c, s, tx, ty}
    __shared__ float2 B[NSHAPES];  // {radx, rady}

    const int t = threadIdx.x;
    if (t < NSHAPES) {
        float a = angles[t];
        // |a| < 0.1: HW v_cos/v_sin exact to ~1e-7 here, no libm slow path.
        A[t] = make_float4(__cosf(a), __sinf(a), trans[2 * t], trans[2 * t + 1]);
        B[t] = make_float2(rads[2 * t], rads[2 * t + 1]);
    }
    __syncthreads();

    const int f4_per_block = BLOCK * PPT / 2;  // 512
    const int base = blockIdx.x * f4_per_block + t;

    // Coalesced float4 loads; each float4 is one packed point-pair.
    v2f X0, Y0, X1, Y1;
    {
        float4 q0, q1;
        if (!GUARD || base < n_f4)          q0 = query4[base];
        else                                q0 = make_float4(0.f, 0.f, 0.f, 0.f);
        if (!GUARD || base + BLOCK < n_f4)  q1 = query4[base + BLOCK];
        else                                q1 = make_float4(0.f, 0.f, 0.f, 0.f);
        X0 = (v2f){q0.x, q0.z}; Y0 = (v2f){q0.y, q0.w};
        X1 = (v2f){q1.x, q1.z}; Y1 = (v2f){q1.y, q1.w};
    }

    v2f sqA = splat(3.0e38f), sqB = splat(3.0e38f);
    v2f inA = splat(0.0f),    inB = splat(0.0f);

    #pragma unroll 2
    for (int k = 0; k < NSHAPES; k += 2) {
        float4 a0 = A[k], a1 = A[k + 1];   // broadcast ds_read_b128
        float2 b0 = B[k], b1 = B[k + 1];   // broadcast ds_read_b64

        v2f m0, s0, m1, s1;
        // point-pair A, shapes k and k+1
        shape_pp(a0.x, a0.y, a0.z, a0.w, b0.x, b0.y, X0, Y0, m0, s0);
        shape_pp(a1.x, a1.y, a1.z, a1.w, b1.x, b1.y, X0, Y0, m1, s1);
        // fminf(fminf(a,b),c) -> v_min3_f32
        sqA = (v2f){fminf(fminf(s0[0], s1[0]), sqA[0]),
                    fminf(fminf(s0[1], s1[1]), sqA[1])};
        inA = (v2f){fminf(fminf(m0[0], m1[0]), inA[0]),
                    fminf(fminf(m0[1], m1[1]), inA[1])};

        // point-pair B, shapes k and k+1
        shape_pp(a0.x, a0.y, a0.z, a0.w, b0.x, b0.y, X1, Y1, m0, s0);
        shape_pp(a1.x, a1.y, a1.z, a1.w, b1.x, b1.y, X1, Y1, m1, s1);
        sqB = (v2f){fminf(fminf(s0[0], s1[0]), sqB[0]),
                    fminf(fminf(s0[1], s1[1]), sqB[1])};
        inB = (v2f){fminf(fminf(m0[0], m1[0]), inB[0]),
                    fminf(fminf(m0[1], m1[1]), inB[1])};
    }

    if (!GUARD || base < n_f4) {
        float r0 = (inA[0] < 0.0f) ? inA[0] : __builtin_amdgcn_sqrtf(sqA[0]);
        float r1 = (inA[1] < 0.0f) ? inA[1] : __builtin_amdgcn_sqrtf(sqA[1]);
        out2[base] = make_float2(r0, r1);
    }
    if (!GUARD || base + BLOCK < n_f4) {
        float r0 = (inB[0] < 0.0f) ? inB[0] : __builtin_amdgcn_sqrtf(sqB[0]);
        float r1 = (inB[1] < 0.0f) ? inB[1] : __builtin_amdgcn_sqrtf(sqB[1]);
        out2[base + BLOCK] = make_float2(r0, r1);
    }
}

extern "C" void kernel_launch(void* const* d_in, const int* in_sizes, int n_in,
                              void* d_out, int out_size, void* d_ws, size_t ws_size,
                              hipStream_t stream) {
    const float* query  = (const float*)d_in[0];
    const float* trans  = (const float*)d_in[1];
    const float* rads   = (const float*)d_in[2];
    const float* angles = (const float*)d_in[3];
    float* out = (float*)d_out;

    const int n_points = in_sizes[0] / 2;   // (N,2) -> N
    const int n_f4 = n_points / 2;          // 2 points per float4
    const int f4_per_block = BLOCK * PPT / 2;
    const int grid = (n_f4 + f4_per_block - 1) / f4_per_block;

    if (n_f4 % f4_per_block == 0) {
        multi_rect_sdf_kernel<false><<<grid, BLOCK, 0, stream>>>(
            (const float4*)query, trans, rads, angles, (float2*)out, n_f4);
    } else {
        multi_rect_sdf_kernel<true><<<grid, BLOCK, 0, stream>>>(
            (const float4*)query, trans, rads, angles, (float2*)out, n_f4);
    }
}